// Round 13
// baseline (216.533 us; speedup 1.0000x reference)
//
#include <hip/hip_runtime.h>
#include <hip/hip_bf16.h>

// ---------------- problem constants ----------------
#define NTOK   8192
#define TOPK   2
#define NROWS  (NTOK*TOPK)      // 16384
#define NEXP   8
#define KDIM   1024             // inner (INTER)
#define NDIM   2048             // output (HIDDEN)
#define TM     128              // tile rows
#define TN     256              // tile cols
#define BK     64
#define MAXYT  136              // sum ceil(cnt_e/128) <= 128+8
#define NXT    (NDIM/TN)        // 8
#define GRID_G (MAXYT*NXT)      // 1088 = 8*136

typedef __bf16 bf16_t;
typedef __bf16 bf16x8 __attribute__((ext_vector_type(8)));
typedef float  f32x4  __attribute__((ext_vector_type(4)));

static_assert(sizeof(bf16x8) == 16, "bf16x8 must be 16B");

// ---------------- ws layout (bytes) ----------------
#define OFF_TW    ((size_t)0)                    // 16384 f32
#define OFF_CNT   ((size_t)(1<<16))              // 8 i32
#define OFF_RL    ((size_t)(1<<18))              // 8*16384 i32
#define OFF_XB    ((size_t)(1<<20))              // 16384*1024 bf16 = 32MB (orig order)
#define OFF_WB    ((size_t)(34u<<20))            // 8*2048*1024 bf16 = 32MB
#define OFF_SCR   ((size_t)(68u<<20))            // 16384*2048 bf16 = 64MB (orig order)

__device__ __forceinline__ void gload_lds16(const bf16_t* g, const char* l) {
  __builtin_amdgcn_global_load_lds(
      (const __attribute__((address_space(1))) void*)g,
      (__attribute__((address_space(3))) void*)(void*)l, 16, 0, 0);
}

// ---------------- 1. fused prep: routing + cvt_x + cvt_w (one launch) --------
// blocks 0..31: routing (softmax+top2+bucket)
// blocks 32..8223: cvt_x (plain fp32->bf16, original order; 2048 chunks/blk)
// blocks 8224..12319: cvt_w (transpose 64x64 tile)
// All three independent -> safe block-range fusion, runs at device BW.
__global__ void prep_kernel(const float* __restrict__ logits,
                            float* __restrict__ tw,
                            int* __restrict__ cnt, int* __restrict__ rowlist,
                            const float* __restrict__ x, bf16_t* __restrict__ xb,
                            const float* __restrict__ w, bf16_t* __restrict__ wb) {
  __shared__ float tf[64*65];
  int bid = blockIdx.x;
  int tid = threadIdx.x;

  if (bid < 32) {
    // ---------- routing ----------
    int t = bid * 256 + tid;
    float4 a = *(const float4*)(logits + (size_t)t*NEXP);
    float4 b = *(const float4*)(logits + (size_t)t*NEXP + 4);
    float l[8] = {a.x, a.y, a.z, a.w, b.x, b.y, b.z, b.w};
    float m = l[0];
#pragma unroll
    for (int i = 1; i < 8; i++) m = fmaxf(m, l[i]);
    float p[8], s = 0.f;
#pragma unroll
    for (int i = 0; i < 8; i++) { p[i] = __expf(l[i] - m); s += p[i]; }
    int e0 = 0; float b0 = p[0];
#pragma unroll
    for (int i = 1; i < 8; i++) if (p[i] > b0) { b0 = p[i]; e0 = i; }
    int e1 = (e0 == 0) ? 1 : 0; float b1 = p[e1];
#pragma unroll
    for (int i = 0; i < 8; i++) if (i != e0 && p[i] > b1) { b1 = p[i]; e1 = i; }
    float inv = 1.f / s;
    tw[2*t]   = b0 * inv;
    tw[2*t+1] = b1 * inv;
    int pos0 = atomicAdd(&cnt[e0], 1);
    rowlist[(size_t)e0*NROWS + pos0] = 2*t;
    int pos1 = atomicAdd(&cnt[e1], 1);
    rowlist[(size_t)e1*NROWS + pos1] = 2*t + 1;
    return;
  }

  if (bid < 32 + 8192) {
    // ---------- cvt_x: one bf16x8 per thread ----------
    size_t i = (size_t)(bid - 32) * 256 + tid;
    float4 v0 = ((const float4*)x)[2*i];
    float4 v1 = ((const float4*)x)[2*i + 1];
    bf16x8 o = { (bf16_t)v0.x, (bf16_t)v0.y, (bf16_t)v0.z, (bf16_t)v0.w,
                 (bf16_t)v1.x, (bf16_t)v1.y, (bf16_t)v1.z, (bf16_t)v1.w };
    *(bf16x8*)(xb + i*8) = o;
    return;
  }

  // ---------- cvt_w: 64n x 64k tile ----------
  int id = bid - (32 + 8192);        // 0..4095
  int e  = id >> 9;                  // 0..7
  int k0 = ((id >> 5) & 15) * 64;    // 0..960
  int n0 = (id & 31) * 64;           // 0..1984
  const float* src = w + (size_t)e*KDIM*NDIM + (size_t)k0*NDIM + n0;
#pragma unroll
  for (int i = 0; i < 4; i++) {
    int idx = tid + i*256;
    int kr  = idx >> 4;
    int nc4 = (idx & 15) * 4;
    float4 v = *(const float4*)(src + (size_t)kr*NDIM + nc4);
    tf[kr*65 + nc4+0] = v.x; tf[kr*65 + nc4+1] = v.y;
    tf[kr*65 + nc4+2] = v.z; tf[kr*65 + nc4+3] = v.w;
  }
  __syncthreads();
  bf16_t* dst = wb + (size_t)e*NDIM*KDIM + (size_t)n0*KDIM + k0;
#pragma unroll
  for (int i = 0; i < 2; i++) {
    int idx = tid + i*256;
    int nr  = idx >> 3;
    int kc  = (idx & 7) * 8;
    bf16x8 o;
#pragma unroll
    for (int j = 0; j < 8; j++) o[j] = (bf16_t)tf[(kc+j)*65 + nr];
    *(bf16x8*)(dst + (size_t)nr*KDIM + kc) = o;
  }
}

// ---------------- 2. grouped GEMM: 128x256, BK=64, gathered A (r8 core) ------
// 8 waves (2M x 4N), per-wave 64x64, 32 MFMA per barrier-pair. LDS 48KB:
// A[128][64] @0, B[256][64] @16384; phys 16B slot = logical ^ (row&7);
// DMA dest linear (t*16); A source rows gathered via rowlist (per-lane).
// Epilogue: tw-scale + scatter to scr in ORIGINAL row order (bf16).
__global__ __launch_bounds__(512)
void gemm_kernel(const bf16_t* __restrict__ xb,     // [NROWS][KDIM] orig order
                 const bf16_t* __restrict__ wb,     // [NEXP][NDIM][KDIM]
                 const int*    __restrict__ cnt,
                 const int*    __restrict__ rowlist,
                 const float*  __restrict__ tw,
                 bf16_t*       __restrict__ scrb) { // [NROWS][NDIM] orig order
  __shared__ char smem[49152];

  // XCD-bijective swizzle: 1088 = 8*136, n-tile fastest
  int bid = blockIdx.x;
  int lin = (bid & 7) * (GRID_G/8) + (bid >> 3);
  int xt  = lin & (NXT-1);
  int yt  = lin >> 3;

  // inline worklist: expert + row range for this 128-row tile
  int e = -1, tilebase = 0, nrows = 0;
  {
    int a0 = 0;
#pragma unroll
    for (int ee = 0; ee < NEXP; ee++) {
      int c  = cnt[ee];
      int nt = (c + TM - 1) >> 7;
      if (yt >= a0 && yt < a0 + nt) {
        e = ee; tilebase = (yt - a0)*TM;
        nrows = c - tilebase; if (nrows > TM) nrows = TM;
      }
      a0 += nt;
    }
  }
  if (e < 0) return;
  const int n0 = xt * TN;

  const int t    = threadIdx.x;
  const int lane = t & 63;
  const int wv   = t >> 6;         // 0..7
  const int wm   = wv >> 2;        // 0..1
  const int wn   = wv & 3;         // 0..3
  const int lr   = lane & 15;
  const int l4   = lane >> 4;

  const int* rl = rowlist + (size_t)e*NROWS + tilebase;

  // ---- staging: thread t -> tile row t>>3 (+64), phys slot t&7, dest linear -
  const int koff = ((t & 7) ^ ((t >> 3) & 7)) * 8;
  int i0 = (t >> 3);        if (i0 >= nrows) i0 = nrows-1;
  int i1 = (t >> 3) + 64;   if (i1 >= nrows) i1 = nrows-1;
  const bf16_t* gA0 = xb + (size_t)rl[i0]*KDIM + koff;
  const bf16_t* gA1 = xb + (size_t)rl[i1]*KDIM + koff;
  const bf16_t* gBb = wb + ((size_t)e*NDIM + n0 + (t >> 3))*KDIM + koff;
  const char* dA = &smem[t*16];
  const char* dB = &smem[16384 + t*16];

  // ---- fragment read offsets (byte, swizzled) ----
  const int aoff0 = (wm*64 + lr)*128 + ((l4 ^ (lr & 7)) << 4);
  const int boff0 = 16384 + (wn*64 + lr)*128 + ((l4 ^ (lr & 7)) << 4);

  f32x4 acc[4][4] = {};

#pragma unroll 1
  for (int kt = 0; kt < KDIM/BK; ++kt) {
    __syncthreads();                 // previous reads done
    gload_lds16(gA0, dA);
    gload_lds16(gA1, dA + 8192);
    gload_lds16(gBb,            dB);
    gload_lds16(gBb + 64*KDIM,  dB + 8192);
    gload_lds16(gBb + 128*KDIM, dB + 16384);
    gload_lds16(gBb + 192*KDIM, dB + 24576);
    gA0 += BK; gA1 += BK; gBb += BK;
    __syncthreads();                 // staged data visible

    bf16x8 af[4][2], bf[4][2];
#pragma unroll
    for (int mi = 0; mi < 4; mi++) {
      af[mi][0] = *(const bf16x8*)&smem[aoff0 + mi*2048];
      af[mi][1] = *(const bf16x8*)&smem[(aoff0 + mi*2048) ^ 64];
    }
#pragma unroll
    for (int ni = 0; ni < 4; ni++) {
      bf[ni][0] = *(const bf16x8*)&smem[boff0 + ni*2048];
      bf[ni][1] = *(const bf16x8*)&smem[(boff0 + ni*2048) ^ 64];
    }
#pragma unroll
    for (int mi = 0; mi < 4; mi++)
#pragma unroll
      for (int ni = 0; ni < 4; ni++) {
        acc[mi][ni] = __builtin_amdgcn_mfma_f32_16x16x32_bf16(af[mi][0], bf[ni][0], acc[mi][ni], 0, 0, 0);
        acc[mi][ni] = __builtin_amdgcn_mfma_f32_16x16x32_bf16(af[mi][1], bf[ni][1], acc[mi][ni], 0, 0, 0);
      }
  }

  // ---- epilogue: tw-scale, scatter to original row order ----
#pragma unroll
  for (int mi = 0; mi < 4; mi++) {
#pragma unroll
    for (int jj = 0; jj < 4; jj++) {
      int rbw = wm*64 + mi*16 + l4*4 + jj;
      if (rbw < nrows) {
        int r = rl[rbw];
        float s = tw[r];
        bf16_t* dst = scrb + (size_t)r*NDIM + n0 + wn*64 + lr;
#pragma unroll
        for (int ni = 0; ni < 4; ni++) dst[ni*16] = (bf16_t)(acc[mi][ni][jj] * s);
      }
    }
  }
}

// ---------------- 3. reduce: out[t] = scr[2t] + scr[2t+1] (pre-scaled) ------
// 512 threads, 2 tokens per block; fully sequential 16KB reads.
__global__ void reduce_kernel(const bf16_t* __restrict__ scr,
                              float* __restrict__ out) {
  int tk = blockIdx.x * 2 + (threadIdx.x >> 8);
  int c  = threadIdx.x & 255;          // 8 cols each
  bf16x8 a = *(const bf16x8*)(scr + ((size_t)2*tk    )*NDIM + c*8);
  bf16x8 b = *(const bf16x8*)(scr + ((size_t)2*tk + 1)*NDIM + c*8);
  float4 o0 = { (float)a[0]+(float)b[0], (float)a[1]+(float)b[1],
                (float)a[2]+(float)b[2], (float)a[3]+(float)b[3] };
  float4 o1 = { (float)a[4]+(float)b[4], (float)a[5]+(float)b[5],
                (float)a[6]+(float)b[6], (float)a[7]+(float)b[7] };
  float* dst = out + (size_t)tk*NDIM + c*8;
  *(float4*)(dst)     = o0;
  *(float4*)(dst + 4) = o1;
}

// ---------------- launch ----------------
extern "C" void kernel_launch(void* const* d_in, const int* in_sizes, int n_in,
                              void* d_out, int out_size, void* d_ws, size_t ws_size,
                              hipStream_t stream) {
  const float* x      = (const float*)d_in[0];
  const float* w      = (const float*)d_in[1];
  const float* logits = (const float*)d_in[2];
  float* out = (float*)d_out;

  char* ws = (char*)d_ws;
  float*  tw      = (float*)(ws + OFF_TW);
  int*    cnt     = (int*)  (ws + OFF_CNT);
  int*    rowlist = (int*)  (ws + OFF_RL);
  bf16_t* xb      = (bf16_t*)(ws + OFF_XB);
  bf16_t* wb      = (bf16_t*)(ws + OFF_WB);
  bf16_t* scrb    = (bf16_t*)(ws + OFF_SCR);

  hipMemsetAsync(cnt, 0, NEXP * sizeof(int), stream);
  prep_kernel<<<32 + 8192 + 4096, 256, 0, stream>>>(logits, tw, cnt, rowlist,
                                                    x, xb, w, wb);
  gemm_kernel<<<GRID_G, 512, 0, stream>>>(xb, wb, cnt, rowlist, tw, scrb);
  reduce_kernel<<<NTOK/2, 512, 0, stream>>>(scrb, out);
}

// Round 14
// 158.512 us; speedup vs baseline: 1.3660x; 1.3660x over previous
//
#include <hip/hip_runtime.h>
#include <hip/hip_bf16.h>

// ---------------- problem constants ----------------
#define NTOK   8192
#define TOPK   2
#define NROWS  (NTOK*TOPK)      // 16384
#define NEXP   8
#define KDIM   1024             // inner (INTER)
#define NDIM   2048             // output (HIDDEN)
#define TM     128              // tile rows
#define TN     256              // tile cols
#define BK     64
#define MAXYT  136              // sum ceil(cnt_e/128) <= 128+8
#define NXT    (NDIM/TN)        // 8
#define GRID_G (MAXYT*NXT)      // 1088 = 8*136

typedef __bf16 bf16_t;
typedef __bf16 bf16x8 __attribute__((ext_vector_type(8)));
typedef float  f32x4  __attribute__((ext_vector_type(4)));

static_assert(sizeof(bf16x8) == 16, "bf16x8 must be 16B");

// ---------------- ws layout (bytes) ----------------
#define OFF_TW    ((size_t)0)                    // 16384 f32
#define OFF_INV   ((size_t)(1<<16))              // 16384 i32
#define OFF_CNT   ((size_t)(1<<17))              // 8 i32
#define OFF_RL    ((size_t)(1<<18))              // 8*16384 i32
#define OFF_XP    ((size_t)(1<<20))              // 16384*1024 bf16 = 32MB (permuted)
#define OFF_WB    ((size_t)(34u<<20))            // 8*2048*1024 bf16 = 32MB
#define OFF_SCR   ((size_t)(68u<<20))            // 16384*2048 bf16 = 64MB (permuted order)

__device__ __forceinline__ void gload_lds16(const bf16_t* g, const char* l) {
  __builtin_amdgcn_global_load_lds(
      (const __attribute__((address_space(1))) void*)g,
      (__attribute__((address_space(3))) void*)(void*)l, 16, 0, 0);
}

#define CVT8(lo,hi) bf16x8{ (bf16_t)(lo).x,(bf16_t)(lo).y,(bf16_t)(lo).z,(bf16_t)(lo).w, \
                            (bf16_t)(hi).x,(bf16_t)(hi).y,(bf16_t)(hi).z,(bf16_t)(hi).w }

// ---------------- 1. routing: softmax + top2, LDS-aggregated bucket ----------
// Per-block LDS counts -> one global atomicAdd per expert per block (512 total
// vs 32K contended). Bucket order varies run-to-run but the OUTPUT is invariant
// (each row's GEMM result is independent of its slot; final sum commutes).
__global__ void routing_kernel(const float* __restrict__ logits,
                               float* __restrict__ tw,
                               int* __restrict__ cnt, int* __restrict__ rowlist) {
  __shared__ int lcnt[NEXP];
  __shared__ int lbase[NEXP];
  int tid = threadIdx.x;
  int t = blockIdx.x * blockDim.x + tid;
  if (tid < NEXP) lcnt[tid] = 0;
  __syncthreads();

  float4 a = *(const float4*)(logits + (size_t)t*NEXP);
  float4 b = *(const float4*)(logits + (size_t)t*NEXP + 4);
  float l[8] = {a.x, a.y, a.z, a.w, b.x, b.y, b.z, b.w};
  float m = l[0];
#pragma unroll
  for (int i = 1; i < 8; i++) m = fmaxf(m, l[i]);
  float p[8], s = 0.f;
#pragma unroll
  for (int i = 0; i < 8; i++) { p[i] = __expf(l[i] - m); s += p[i]; }
  int e0 = 0; float b0 = p[0];
#pragma unroll
  for (int i = 1; i < 8; i++) if (p[i] > b0) { b0 = p[i]; e0 = i; }
  int e1 = (e0 == 0) ? 1 : 0; float b1 = p[e1];
#pragma unroll
  for (int i = 0; i < 8; i++) if (i != e0 && p[i] > b1) { b1 = p[i]; e1 = i; }
  float inv = 1.f / s;
  tw[2*t]   = b0 * inv;
  tw[2*t+1] = b1 * inv;

  int lp0 = atomicAdd(&lcnt[e0], 1);
  int lp1 = atomicAdd(&lcnt[e1], 1);
  __syncthreads();
  if (tid < NEXP) lbase[tid] = atomicAdd(&cnt[tid], lcnt[tid]);
  __syncthreads();
  rowlist[(size_t)e0*NROWS + lbase[e0] + lp0] = 2*t;
  rowlist[(size_t)e1*NROWS + lbase[e1] + lp1] = 2*t + 1;
}

// ---------------- 2. fused cvt: cvt_x_perm (blocks 0..2047) + cvt_w (2048..6143)
// cvt_x_perm: 8 rows/block, 64 threads/row, 16 cols/thread -> 4 independent
// float4 loads in flight (ILP fix for the r13 latency-bound symptom).
// cvt_w: 64x64 transpose tile via LDS (2-way conflicts only).
__global__ void cvt_kernel(const float* __restrict__ x,
                           const int* __restrict__ cnt,
                           const int* __restrict__ rowlist,
                           bf16_t* __restrict__ xp,
                           int* __restrict__ inv,
                           const float* __restrict__ w,
                           bf16_t* __restrict__ wb) {
  __shared__ float tf[64*65];
  int bid = blockIdx.x;
  int tid = threadIdx.x;

  if (bid < 2048) {
    // ---------- cvt_x_perm ----------
    int rid = bid * 8 + (tid >> 6);              // slot 0..16383
    int c   = (tid & 63) * 16;                   // col start
    int e = 0, base = 0, acc = 0;
#pragma unroll
    for (int ee = 0; ee < NEXP; ee++) {
      int ce = cnt[ee];
      if (rid >= acc && rid < acc + ce) { e = ee; base = acc; }
      acc += ce;
    }
    int src = rowlist[(size_t)e*NROWS + (rid - base)];
    const float* sp = x + (size_t)src*KDIM + c;
    float4 v0 = *(const float4*)(sp);
    float4 v1 = *(const float4*)(sp + 4);
    float4 v2 = *(const float4*)(sp + 8);
    float4 v3 = *(const float4*)(sp + 12);
    bf16_t* dp = xp + (size_t)rid*KDIM + c;
    *(bf16x8*)(dp)     = CVT8(v0, v1);
    *(bf16x8*)(dp + 8) = CVT8(v2, v3);
    if ((tid & 63) == 0) inv[src] = rid;
    return;
  }

  // ---------- cvt_w: 64n x 64k tile ----------
  int id = bid - 2048;               // 0..4095
  int e  = id >> 9;                  // 0..7
  int k0 = ((id >> 5) & 15) * 64;    // 0..960
  int n0 = (id & 31) * 64;           // 0..1984
  const float* src = w + (size_t)e*KDIM*NDIM + (size_t)k0*NDIM + n0;
#pragma unroll
  for (int i = 0; i < 2; i++) {
    int idx = tid + i*512;           // 0..1023
    int kr  = idx >> 4;
    int nc4 = (idx & 15) * 4;
    float4 v = *(const float4*)(src + (size_t)kr*NDIM + nc4);
    tf[kr*65 + nc4+0] = v.x; tf[kr*65 + nc4+1] = v.y;
    tf[kr*65 + nc4+2] = v.z; tf[kr*65 + nc4+3] = v.w;
  }
  __syncthreads();
  bf16_t* dst = wb + (size_t)e*NDIM*KDIM + (size_t)n0*KDIM + k0;
  {
    int idx = tid;                   // 0..511
    int nr  = idx >> 3;
    int kc  = (idx & 7) * 8;
    bf16x8 o;
#pragma unroll
    for (int j = 0; j < 8; j++) o[j] = (bf16_t)tf[(kc+j)*65 + nr];
    *(bf16x8*)(dst + (size_t)nr*KDIM + kc) = o;
  }
}

// ---------------- 3. dense per-expert GEMM: 128x256, BK=64 (r12-proven) -----
__global__ __launch_bounds__(512)
void gemm_kernel(const bf16_t* __restrict__ xp,     // [NROWS][KDIM] permuted
                 const bf16_t* __restrict__ wb,     // [NEXP][NDIM][KDIM]
                 const int*    __restrict__ cnt,
                 bf16_t*       __restrict__ scrb) { // [NROWS][NDIM] permuted
  __shared__ char smem[49152];

  // XCD-bijective swizzle: 1088 = 8*136, n-tile fastest
  int bid = blockIdx.x;
  int lin = (bid & 7) * (GRID_G/8) + (bid >> 3);
  int xt  = lin & (NXT-1);
  int yt  = lin >> 3;

  // inline worklist: expert + row range for this 128-row tile
  int e = -1, rowbase = 0, nrows = 0;
  {
    int a0 = 0, rb = 0;
#pragma unroll
    for (int ee = 0; ee < NEXP; ee++) {
      int c  = cnt[ee];
      int nt = (c + TM - 1) >> 7;
      if (yt >= a0 && yt < a0 + nt) {
        e = ee; rowbase = rb + (yt - a0)*TM;
        nrows = c - (yt - a0)*TM; if (nrows > TM) nrows = TM;
      }
      a0 += nt; rb += c;
    }
  }
  if (e < 0) return;
  const int n0 = xt * TN;

  const int t    = threadIdx.x;
  const int lane = t & 63;
  const int wv   = t >> 6;         // 0..7
  const int wm   = wv >> 2;        // 0..1
  const int wn   = wv & 3;         // 0..3
  const int lr   = lane & 15;
  const int l4   = lane >> 4;

  // ---- staging: thread t -> row t>>3 (+64i), phys slot t&7, dest linear ----
  const int koff = ((t & 7) ^ ((t >> 3) & 7)) * 8;
  int ar0 = rowbase + (t >> 3);       if (ar0 > NROWS-1) ar0 = NROWS-1;
  int ar1 = rowbase + (t >> 3) + 64;  if (ar1 > NROWS-1) ar1 = NROWS-1;
  const bf16_t* gA0 = xp + (size_t)ar0*KDIM + koff;
  const bf16_t* gA1 = xp + (size_t)ar1*KDIM + koff;
  const bf16_t* gBb = wb + ((size_t)e*NDIM + n0 + (t >> 3))*KDIM + koff;
  const char* dA = &smem[t*16];
  const char* dB = &smem[16384 + t*16];

  // ---- fragment read offsets (byte, swizzled) ----
  const int aoff0 = (wm*64 + lr)*128 + ((l4 ^ (lr & 7)) << 4);
  const int boff0 = 16384 + (wn*64 + lr)*128 + ((l4 ^ (lr & 7)) << 4);

  f32x4 acc[4][4] = {};

#pragma unroll 1
  for (int kt = 0; kt < KDIM/BK; ++kt) {
    __syncthreads();                 // previous reads done
    gload_lds16(gA0, dA);
    gload_lds16(gA1, dA + 8192);
    gload_lds16(gBb,            dB);
    gload_lds16(gBb + 64*KDIM,  dB + 8192);
    gload_lds16(gBb + 128*KDIM, dB + 16384);
    gload_lds16(gBb + 192*KDIM, dB + 24576);
    gA0 += BK; gA1 += BK; gBb += BK;
    __syncthreads();                 // staged data visible

    bf16x8 af[4][2], bf[4][2];
#pragma unroll
    for (int mi = 0; mi < 4; mi++) {
      af[mi][0] = *(const bf16x8*)&smem[aoff0 + mi*2048];
      af[mi][1] = *(const bf16x8*)&smem[(aoff0 + mi*2048) ^ 64];
    }
#pragma unroll
    for (int ni = 0; ni < 4; ni++) {
      bf[ni][0] = *(const bf16x8*)&smem[boff0 + ni*2048];
      bf[ni][1] = *(const bf16x8*)&smem[(boff0 + ni*2048) ^ 64];
    }
#pragma unroll
    for (int mi = 0; mi < 4; mi++)
#pragma unroll
      for (int ni = 0; ni < 4; ni++) {
        acc[mi][ni] = __builtin_amdgcn_mfma_f32_16x16x32_bf16(af[mi][0], bf[ni][0], acc[mi][ni], 0, 0, 0);
        acc[mi][ni] = __builtin_amdgcn_mfma_f32_16x16x32_bf16(af[mi][1], bf[ni][1], acc[mi][ni], 0, 0, 0);
      }
  }

  // ---- epilogue: sequential slot rows ----
#pragma unroll
  for (int mi = 0; mi < 4; mi++) {
#pragma unroll
    for (int jj = 0; jj < 4; jj++) {
      int rbw = wm*64 + mi*16 + l4*4 + jj;
      if (rbw < nrows) {
        bf16_t* dst = scrb + (size_t)(rowbase + rbw)*NDIM + n0 + wn*64 + lr;
#pragma unroll
        for (int ni = 0; ni < 4; ni++) dst[ni*16] = (bf16_t)acc[mi][ni][jj];
      }
    }
  }
}

// ---------------- 4. reduce: 16 cols/thread -> 4 indep 16B loads in flight ---
__global__ void reduce_kernel(const bf16_t* __restrict__ scr,
                              const int* __restrict__ inv,
                              const float* __restrict__ tw,
                              float* __restrict__ out) {
  int g  = blockIdx.x * 512 + threadIdx.x;
  int tk = g >> 7;                     // 128 threads per token
  int c  = (g & 127) * 16;
  int2  iv = *(const int2*)(inv + 2*tk);
  float w0 = tw[2*tk], w1 = tw[2*tk+1];
  const bf16_t* pa = scr + (size_t)iv.x*NDIM + c;
  const bf16_t* pb = scr + (size_t)iv.y*NDIM + c;
  bf16x8 a0 = *(const bf16x8*)(pa);
  bf16x8 a1 = *(const bf16x8*)(pa + 8);
  bf16x8 b0 = *(const bf16x8*)(pb);
  bf16x8 b1 = *(const bf16x8*)(pb + 8);
  float* dst = out + (size_t)tk*NDIM + c;
#pragma unroll
  for (int h = 0; h < 2; h++) {
    bf16x8 av = h ? a1 : a0;
    bf16x8 bv = h ? b1 : b0;
    float4 o0 = { w0*(float)av[0]+w1*(float)bv[0], w0*(float)av[1]+w1*(float)bv[1],
                  w0*(float)av[2]+w1*(float)bv[2], w0*(float)av[3]+w1*(float)bv[3] };
    float4 o1 = { w0*(float)av[4]+w1*(float)bv[4], w0*(float)av[5]+w1*(float)bv[5],
                  w0*(float)av[6]+w1*(float)bv[6], w0*(float)av[7]+w1*(float)bv[7] };
    *(float4*)(dst + h*8)     = o0;
    *(float4*)(dst + h*8 + 4) = o1;
  }
}

// ---------------- launch ----------------
extern "C" void kernel_launch(void* const* d_in, const int* in_sizes, int n_in,
                              void* d_out, int out_size, void* d_ws, size_t ws_size,
                              hipStream_t stream) {
  const float* x      = (const float*)d_in[0];
  const float* w      = (const float*)d_in[1];
  const float* logits = (const float*)d_in[2];
  float* out = (float*)d_out;

  char* ws = (char*)d_ws;
  float*  tw      = (float*)(ws + OFF_TW);
  int*    inv     = (int*)  (ws + OFF_INV);
  int*    cnt     = (int*)  (ws + OFF_CNT);
  int*    rowlist = (int*)  (ws + OFF_RL);
  bf16_t* xp      = (bf16_t*)(ws + OFF_XP);
  bf16_t* wb      = (bf16_t*)(ws + OFF_WB);
  bf16_t* scrb    = (bf16_t*)(ws + OFF_SCR);

  hipMemsetAsync(cnt, 0, NEXP * sizeof(int), stream);
  routing_kernel<<<NTOK/256, 256, 0, stream>>>(logits, tw, cnt, rowlist);
  cvt_kernel<<<2048 + 4096, 512, 0, stream>>>(x, cnt, rowlist, xp, inv, w, wb);
  gemm_kernel<<<GRID_G, 512, 0, stream>>>(xp, wb, cnt, scrb);
  reduce_kernel<<<NTOK*NDIM/16/512, 512, 0, stream>>>(scrb, inv, tw, out);
}

// Round 15
// 157.915 us; speedup vs baseline: 1.3712x; 1.0038x over previous
//
#include <hip/hip_runtime.h>
#include <hip/hip_bf16.h>

// ---------------- problem constants ----------------
#define NTOK   8192
#define TOPK   2
#define NROWS  (NTOK*TOPK)      // 16384
#define NEXP   8
#define KDIM   1024             // inner (INTER)
#define NDIM   2048             // output (HIDDEN)
#define TM     128              // tile rows
#define TN     128              // tile cols
#define BK     64
#define MAXYT  136              // sum ceil(cnt_e/128) <= 128+8
#define NXT    (NDIM/TN)        // 16
#define GRID_G (MAXYT*NXT)      // 2176 = 8*272

typedef __bf16 bf16_t;
typedef __bf16 bf16x8 __attribute__((ext_vector_type(8)));
typedef float  f32x4  __attribute__((ext_vector_type(4)));

static_assert(sizeof(bf16x8) == 16, "bf16x8 must be 16B");

// ---------------- ws layout (bytes) ----------------
#define OFF_TW    ((size_t)0)                    // 16384 f32
#define OFF_INV   ((size_t)(1<<16))              // 16384 i32
#define OFF_CNT   ((size_t)(1<<17))              // 8 i32
#define OFF_RL    ((size_t)(1<<18))              // 8*16384 i32
#define OFF_XP    ((size_t)(1<<20))              // 16384*1024 bf16 = 32MB (permuted)
#define OFF_WB    ((size_t)(34u<<20))            // 8*2048*1024 bf16 = 32MB
#define OFF_SCR   ((size_t)(68u<<20))            // 16384*2048 bf16 = 64MB (permuted order)

__device__ __forceinline__ void gload_lds16(const bf16_t* g, const char* l) {
  __builtin_amdgcn_global_load_lds(
      (const __attribute__((address_space(1))) void*)g,
      (__attribute__((address_space(3))) void*)(void*)l, 16, 0, 0);
}

#define CVT8(lo,hi) bf16x8{ (bf16_t)(lo).x,(bf16_t)(lo).y,(bf16_t)(lo).z,(bf16_t)(lo).w, \
                            (bf16_t)(hi).x,(bf16_t)(hi).y,(bf16_t)(hi).z,(bf16_t)(hi).w }

// ---------------- 1. routing: softmax + top2, LDS-aggregated bucket ----------
__global__ void routing_kernel(const float* __restrict__ logits,
                               float* __restrict__ tw,
                               int* __restrict__ cnt, int* __restrict__ rowlist) {
  __shared__ int lcnt[NEXP];
  __shared__ int lbase[NEXP];
  int tid = threadIdx.x;
  int t = blockIdx.x * blockDim.x + tid;
  if (tid < NEXP) lcnt[tid] = 0;
  __syncthreads();

  float4 a = *(const float4*)(logits + (size_t)t*NEXP);
  float4 b = *(const float4*)(logits + (size_t)t*NEXP + 4);
  float l[8] = {a.x, a.y, a.z, a.w, b.x, b.y, b.z, b.w};
  float m = l[0];
#pragma unroll
  for (int i = 1; i < 8; i++) m = fmaxf(m, l[i]);
  float p[8], s = 0.f;
#pragma unroll
  for (int i = 0; i < 8; i++) { p[i] = __expf(l[i] - m); s += p[i]; }
  int e0 = 0; float b0 = p[0];
#pragma unroll
  for (int i = 1; i < 8; i++) if (p[i] > b0) { b0 = p[i]; e0 = i; }
  int e1 = (e0 == 0) ? 1 : 0; float b1 = p[e1];
#pragma unroll
  for (int i = 0; i < 8; i++) if (i != e0 && p[i] > b1) { b1 = p[i]; e1 = i; }
  float inv = 1.f / s;
  tw[2*t]   = b0 * inv;
  tw[2*t+1] = b1 * inv;

  int lp0 = atomicAdd(&lcnt[e0], 1);
  int lp1 = atomicAdd(&lcnt[e1], 1);
  __syncthreads();
  if (tid < NEXP) lbase[tid] = atomicAdd(&cnt[tid], lcnt[tid]);
  __syncthreads();
  rowlist[(size_t)e0*NROWS + lbase[e0] + lp0] = 2*t;
  rowlist[(size_t)e1*NROWS + lbase[e1] + lp1] = 2*t + 1;
}

// ---------------- 2. fused cvt: cvt_x_perm (blocks 0..2047) + cvt_w (2048..6143)
__global__ void cvt_kernel(const float* __restrict__ x,
                           const int* __restrict__ cnt,
                           const int* __restrict__ rowlist,
                           bf16_t* __restrict__ xp,
                           int* __restrict__ inv,
                           const float* __restrict__ w,
                           bf16_t* __restrict__ wb) {
  __shared__ float tf[64*65];
  int bid = blockIdx.x;
  int tid = threadIdx.x;

  if (bid < 2048) {
    // ---------- cvt_x_perm: 8 rows/block, 64 thr/row, 16 cols/thread ----------
    int rid = bid * 8 + (tid >> 6);              // slot 0..16383
    int c   = (tid & 63) * 16;                   // col start
    int e = 0, base = 0, acc = 0;
#pragma unroll
    for (int ee = 0; ee < NEXP; ee++) {
      int ce = cnt[ee];
      if (rid >= acc && rid < acc + ce) { e = ee; base = acc; }
      acc += ce;
    }
    int src = rowlist[(size_t)e*NROWS + (rid - base)];
    const float* sp = x + (size_t)src*KDIM + c;
    float4 v0 = *(const float4*)(sp);
    float4 v1 = *(const float4*)(sp + 4);
    float4 v2 = *(const float4*)(sp + 8);
    float4 v3 = *(const float4*)(sp + 12);
    bf16_t* dp = xp + (size_t)rid*KDIM + c;
    *(bf16x8*)(dp)     = CVT8(v0, v1);
    *(bf16x8*)(dp + 8) = CVT8(v2, v3);
    if ((tid & 63) == 0) inv[src] = rid;
    return;
  }

  // ---------- cvt_w: 64n x 64k tile ----------
  int id = bid - 2048;               // 0..4095
  int e  = id >> 9;                  // 0..7
  int k0 = ((id >> 5) & 15) * 64;    // 0..960
  int n0 = (id & 31) * 64;           // 0..1984
  const float* src = w + (size_t)e*KDIM*NDIM + (size_t)k0*NDIM + n0;
#pragma unroll
  for (int i = 0; i < 2; i++) {
    int idx = tid + i*512;           // 0..1023
    int kr  = idx >> 4;
    int nc4 = (idx & 15) * 4;
    float4 v = *(const float4*)(src + (size_t)kr*NDIM + nc4);
    tf[kr*65 + nc4+0] = v.x; tf[kr*65 + nc4+1] = v.y;
    tf[kr*65 + nc4+2] = v.z; tf[kr*65 + nc4+3] = v.w;
  }
  __syncthreads();
  bf16_t* dst = wb + (size_t)e*NDIM*KDIM + (size_t)n0*KDIM + k0;
  {
    int idx = tid;                   // 0..511
    int nr  = idx >> 3;
    int kc  = (idx & 7) * 8;
    bf16x8 o;
#pragma unroll
    for (int j = 0; j < 8; j++) o[j] = (bf16_t)tf[(kc+j)*65 + nr];
    *(bf16x8*)(dst + (size_t)nr*KDIM + kc) = o;
  }
}

// ---------------- 3. dense per-expert GEMM: 128x128, BK=64, 4 waves ---------
// Guide tile-space: 128^2 = 912 TF > 128x256 = 823 at this structure (m103/m105).
// 32KB LDS -> 5 blocks/CU (vs 3) => more cross-block overlap to hide DMA drain
// (the r10-proven currency of this 2-barrier family). 4 waves (2M x 2N), each
// 64x64 out, 32 MFMA per barrier-pair. Swizzle: phys 16B slot = logical^(row&7).
__global__ __launch_bounds__(256)
void gemm_kernel(const bf16_t* __restrict__ xp,     // [NROWS][KDIM] permuted
                 const bf16_t* __restrict__ wb,     // [NEXP][NDIM][KDIM]
                 const int*    __restrict__ cnt,
                 bf16_t*       __restrict__ scrb) { // [NROWS][NDIM] permuted
  __shared__ char smem[32768];   // A[128][64] @0, B[128][64] @16384

  // XCD-bijective swizzle: 2176 = 8*272, n-tile fastest
  int bid = blockIdx.x;
  int lin = (bid & 7) * (GRID_G/8) + (bid >> 3);
  int xt  = lin & (NXT-1);
  int yt  = lin >> 4;

  // inline worklist: expert + row range for this 128-row tile
  int e = -1, rowbase = 0, nrows = 0;
  {
    int a0 = 0, rb = 0;
#pragma unroll
    for (int ee = 0; ee < NEXP; ee++) {
      int c  = cnt[ee];
      int nt = (c + TM - 1) >> 7;
      if (yt >= a0 && yt < a0 + nt) {
        e = ee; rowbase = rb + (yt - a0)*TM;
        nrows = c - (yt - a0)*TM; if (nrows > TM) nrows = TM;
      }
      a0 += nt; rb += c;
    }
  }
  if (e < 0) return;
  const int n0 = xt * TN;

  const int t    = threadIdx.x;
  const int lane = t & 63;
  const int wv   = t >> 6;         // 0..3
  const int wm   = wv >> 1;        // 0..1
  const int wn   = wv & 1;         // 0..1
  const int lr   = lane & 15;
  const int l4   = lane >> 4;

  // ---- staging: thread t -> row (t>>3) + 32u, phys slot t&7, dest linear ----
  const int koff = ((t & 7) ^ ((t >> 3) & 7)) * 8;
  int r0 = rowbase + (t >> 3);
  int a0r = r0;      if (a0r > NROWS-1) a0r = NROWS-1;
  int a1r = r0+32;   if (a1r > NROWS-1) a1r = NROWS-1;
  int a2r = r0+64;   if (a2r > NROWS-1) a2r = NROWS-1;
  int a3r = r0+96;   if (a3r > NROWS-1) a3r = NROWS-1;
  const bf16_t* gA0 = xp + (size_t)a0r*KDIM + koff;
  const bf16_t* gA1 = xp + (size_t)a1r*KDIM + koff;
  const bf16_t* gA2 = xp + (size_t)a2r*KDIM + koff;
  const bf16_t* gA3 = xp + (size_t)a3r*KDIM + koff;
  const bf16_t* gBb = wb + ((size_t)e*NDIM + n0 + (t >> 3))*KDIM + koff;
  const char* dA = &smem[t*16];
  const char* dB = &smem[16384 + t*16];

  // ---- fragment read offsets (byte, swizzled) ----
  const int aoff0 = (wm*64 + lr)*128 + ((l4 ^ (lr & 7)) << 4);
  const int boff0 = 16384 + (wn*64 + lr)*128 + ((l4 ^ (lr & 7)) << 4);

  f32x4 acc[4][4] = {};

#pragma unroll 1
  for (int kt = 0; kt < KDIM/BK; ++kt) {
    __syncthreads();                 // previous reads done
    gload_lds16(gA0, dA);
    gload_lds16(gA1, dA + 4096);
    gload_lds16(gA2, dA + 8192);
    gload_lds16(gA3, dA + 12288);
    gload_lds16(gBb,           dB);
    gload_lds16(gBb + 32*KDIM, dB + 4096);
    gload_lds16(gBb + 64*KDIM, dB + 8192);
    gload_lds16(gBb + 96*KDIM, dB + 12288);
    gA0 += BK; gA1 += BK; gA2 += BK; gA3 += BK; gBb += BK;
    __syncthreads();                 // staged data visible

    bf16x8 af[4][2], bf[4][2];
#pragma unroll
    for (int mi = 0; mi < 4; mi++) {
      af[mi][0] = *(const bf16x8*)&smem[aoff0 + mi*2048];
      af[mi][1] = *(const bf16x8*)&smem[(aoff0 + mi*2048) ^ 64];
    }
#pragma unroll
    for (int ni = 0; ni < 4; ni++) {
      bf[ni][0] = *(const bf16x8*)&smem[boff0 + ni*2048];
      bf[ni][1] = *(const bf16x8*)&smem[(boff0 + ni*2048) ^ 64];
    }
#pragma unroll
    for (int mi = 0; mi < 4; mi++)
#pragma unroll
      for (int ni = 0; ni < 4; ni++) {
        acc[mi][ni] = __builtin_amdgcn_mfma_f32_16x16x32_bf16(af[mi][0], bf[ni][0], acc[mi][ni], 0, 0, 0);
        acc[mi][ni] = __builtin_amdgcn_mfma_f32_16x16x32_bf16(af[mi][1], bf[ni][1], acc[mi][ni], 0, 0, 0);
      }
  }

  // ---- epilogue: sequential slot rows ----
#pragma unroll
  for (int mi = 0; mi < 4; mi++) {
#pragma unroll
    for (int jj = 0; jj < 4; jj++) {
      int rbw = wm*64 + mi*16 + l4*4 + jj;
      if (rbw < nrows) {
        bf16_t* dst = scrb + (size_t)(rowbase + rbw)*NDIM + n0 + wn*64 + lr;
#pragma unroll
        for (int ni = 0; ni < 4; ni++) dst[ni*16] = (bf16_t)acc[mi][ni][jj];
      }
    }
  }
}

// ---------------- 4. reduce: 16 cols/thread -> 4 indep 16B loads in flight ---
__global__ void reduce_kernel(const bf16_t* __restrict__ scr,
                              const int* __restrict__ inv,
                              const float* __restrict__ tw,
                              float* __restrict__ out) {
  int g  = blockIdx.x * 512 + threadIdx.x;
  int tk = g >> 7;                     // 128 threads per token
  int c  = (g & 127) * 16;
  int2  iv = *(const int2*)(inv + 2*tk);
  float w0 = tw[2*tk], w1 = tw[2*tk+1];
  const bf16_t* pa = scr + (size_t)iv.x*NDIM + c;
  const bf16_t* pb = scr + (size_t)iv.y*NDIM + c;
  bf16x8 a0 = *(const bf16x8*)(pa);
  bf16x8 a1 = *(const bf16x8*)(pa + 8);
  bf16x8 b0 = *(const bf16x8*)(pb);
  bf16x8 b1 = *(const bf16x8*)(pb + 8);
  float* dst = out + (size_t)tk*NDIM + c;
#pragma unroll
  for (int h = 0; h < 2; h++) {
    bf16x8 av = h ? a1 : a0;
    bf16x8 bv = h ? b1 : b0;
    float4 o0 = { w0*(float)av[0]+w1*(float)bv[0], w0*(float)av[1]+w1*(float)bv[1],
                  w0*(float)av[2]+w1*(float)bv[2], w0*(float)av[3]+w1*(float)bv[3] };
    float4 o1 = { w0*(float)av[4]+w1*(float)bv[4], w0*(float)av[5]+w1*(float)bv[5],
                  w0*(float)av[6]+w1*(float)bv[6], w0*(float)av[7]+w1*(float)bv[7] };
    *(float4*)(dst + h*8)     = o0;
    *(float4*)(dst + h*8 + 4) = o1;
  }
}

// ---------------- launch ----------------
extern "C" void kernel_launch(void* const* d_in, const int* in_sizes, int n_in,
                              void* d_out, int out_size, void* d_ws, size_t ws_size,
                              hipStream_t stream) {
  const float* x      = (const float*)d_in[0];
  const float* w      = (const float*)d_in[1];
  const float* logits = (const float*)d_in[2];
  float* out = (float*)d_out;

  char* ws = (char*)d_ws;
  float*  tw      = (float*)(ws + OFF_TW);
  int*    inv     = (int*)  (ws + OFF_INV);
  int*    cnt     = (int*)  (ws + OFF_CNT);
  int*    rowlist = (int*)  (ws + OFF_RL);
  bf16_t* xp      = (bf16_t*)(ws + OFF_XP);
  bf16_t* wb      = (bf16_t*)(ws + OFF_WB);
  bf16_t* scrb    = (bf16_t*)(ws + OFF_SCR);

  hipMemsetAsync(cnt, 0, NEXP * sizeof(int), stream);
  routing_kernel<<<NTOK/256, 256, 0, stream>>>(logits, tw, cnt, rowlist);
  cvt_kernel<<<2048 + 4096, 512, 0, stream>>>(x, cnt, rowlist, xp, inv, w, wb);
  gemm_kernel<<<GRID_G, 256, 0, stream>>>(xp, wb, cnt, scrb);
  reduce_kernel<<<NTOK*NDIM/16/512, 512, 0, stream>>>(scrb, inv, tw, out);
}